// Round 1
// 54.008 us; speedup vs baseline: 1.0389x; 1.0389x over previous
//
#include <hip/hip_runtime.h>

#define NM   512   // N_MODES
#define KTH  511   // number of thetas = N_MODES - 1
#define ROWS 8     // rows (= waves) per block
#define NTHR (ROWS * 64)
// stride-9 padding: index i lives at i + i/8  ->  lane accesses at stride 8
// become stride 9 (coprime with 32 banks) => conflict-free
#define PADI(i) ((i) + ((i) >> 3))
#define PLEN 576   // PADI(511) = 574, rounded up

// One wave per row r of U (8 rows per block).
// Row r (row-major):
//   U[r][j] = 0                      for j > r+1
//   U[r][r+1] = sin(theta_r)         (r <= 510)
//   cascade: Q = cos(theta_r) (or 1 for r=511);
//            for i = r-1 .. 0: U[r][i+1] = cos(theta_i)*Q; Q *= -sin(theta_i);
//            U[r][0] = Q
// The block cooperatively computes sin/cos of all thetas ONCE into padded LDS
// tables (1 sinf + 1 cosf per thread, vs 8+8 per lane before); each wave then
// reads its chain values from LDS. Multiplication order is unchanged, so the
// output is bit-identical to the per-row recompute version.
__global__ __launch_bounds__(NTHR) void unitary_rows(const float* __restrict__ thetas,
                                                     float* __restrict__ U) {
    const int tid  = threadIdx.x;
    const int lane = tid & 63;
    const int w    = tid >> 6;
    const int r    = blockIdx.x * ROWS + w;   // row 0..511

    __shared__ float c_tab[PLEN];
    __shared__ float s_tab[PLEN];
    __shared__ float rowpad[ROWS][PLEN];

    // ---- cooperative sin/cos table (NTHR == 512 >= KTH) ----
    if (tid < KTH) {
        const float th = thetas[tid];
        c_tab[PADI(tid)] = cosf(th);
        s_tab[PADI(tid)] = sinf(th);
    }
    __syncthreads();

    const int   L  = r;                                    // cascade length
    const float cr = (r < KTH) ? c_tab[PADI(r)] : 1.0f;    // chain seed

    // per-lane chunk: local sin/cos from table and product of (-s_i)
    float sv[8], cv[8];
    float p = 1.0f;
    #pragma unroll
    for (int mm = 0; mm < 8; ++mm) {
        const int m = lane * 8 + mm;
        if (m < L) {
            const int i = r - 1 - m;
            sv[mm] = s_tab[PADI(i)];
            cv[mm] = c_tab[PADI(i)];
            p *= -sv[mm];
        } else {
            sv[mm] = 0.0f;
            cv[mm] = 0.0f;
        }
    }

    // inclusive multiplicative scan across 64 lanes
    float x = p;
    #pragma unroll
    for (int off = 1; off < 64; off <<= 1) {
        const float y = __shfl_up(x, off, 64);
        if (lane >= off) x *= y;
    }
    // exclusive prefix product for this lane
    float pre = __shfl_up(x, 1, 64);
    if (lane == 0) pre = 1.0f;

    // walk this lane's 8 chain positions (padded writes: conflict-free)
    float Q = cr * pre;
    #pragma unroll
    for (int mm = 0; mm < 8; ++mm) {
        const int m = lane * 8 + mm;
        if (m < L) {
            const int i = r - 1 - m;
            rowpad[w][PADI(i + 1)] = cv[mm] * Q;
            Q = -sv[mm] * Q;
            if (m == L - 1) rowpad[w][0] = Q;   // end of chain -> column 0
        }
    }
    if (r == 0 && lane == 0)  rowpad[w][0] = cr;                      // empty chain
    if (r < KTH && lane == 0) rowpad[w][PADI(r + 1)] = s_tab[PADI(r)]; // super-diag
    __syncthreads();

    // coalesced dump: 2 x float4 per lane; mask columns > r+1 to zero
    // (replaces the old pre-zero pass + extra barrier)
    float4* dst = (float4*)(U + (size_t)r * NM);
    #pragma unroll
    for (int t = 0; t < 2; ++t) {
        const int j  = lane + 64 * t;
        const int c0 = 4 * j;
        float4 v;
        v.x = (c0     <= r + 1) ? rowpad[w][PADI(c0)]     : 0.0f;
        v.y = (c0 + 1 <= r + 1) ? rowpad[w][PADI(c0 + 1)] : 0.0f;
        v.z = (c0 + 2 <= r + 1) ? rowpad[w][PADI(c0 + 2)] : 0.0f;
        v.w = (c0 + 3 <= r + 1) ? rowpad[w][PADI(c0 + 3)] : 0.0f;
        dst[j] = v;
    }
}

extern "C" void kernel_launch(void* const* d_in, const int* in_sizes, int n_in,
                              void* d_out, int out_size, void* d_ws, size_t ws_size,
                              hipStream_t stream) {
    const float* thetas = (const float*)d_in[0];
    float*       U      = (float*)d_out;
    unitary_rows<<<NM / ROWS, NTHR, 0, stream>>>(thetas, U);
}